// Round 15
// baseline (243.906 us; speedup 1.0000x reference)
//
#include <hip/hip_runtime.h>
#include <hip/hip_cooperative_groups.h>
#include <math.h>

#define Bb 2
#define Ss 512
#define Dd 512
#define Hh 8
#define HDd 64
#define BS (Bb*Ss)

#if __has_builtin(__builtin_amdgcn_exp2f)
#define EXP2F(x) __builtin_amdgcn_exp2f(x)
#else
#define EXP2F(x) exp2f(x)
#endif
#if __has_builtin(__builtin_amdgcn_rcpf)
#define RCPF(x) __builtin_amdgcn_rcpf(x)
#else
#define RCPF(x) (1.0f/(x))
#endif

typedef float v4f __attribute__((ext_vector_type(4)));
typedef short v8s __attribute__((ext_vector_type(8)));

struct HL { short h, l; };

// RNE fp32 -> bf16 split: x ~= hi + lo, both bf16-representable.
__device__ __forceinline__ HL split1(float x) {
  unsigned u = __builtin_bit_cast(unsigned, x);
  unsigned h = (u + 0x7fffu + ((u >> 16) & 1u)) >> 16;
  float hf = __builtin_bit_cast(float, h << 16);
  float lo = x - hf;
  unsigned ul = __builtin_bit_cast(unsigned, lo);
  unsigned l = (ul + 0x7fffu + ((ul >> 16) & 1u)) >> 16;
  HL r; r.h = (short)h; r.l = (short)l;
  return r;
}

__device__ __forceinline__ void split8p(const float* __restrict__ xp, v8s& ah, v8s& al) {
#pragma unroll
  for (int j = 0; j < 8; j++) {
    const HL r = split1(xp[j]);
    ah[j] = r.h; al[j] = r.l;
  }
}

__device__ __forceinline__ void split8v(float4 x0, float4 x1, v8s& ah, v8s& al) {
  HL r;
  r = split1(x0.x); ah[0] = r.h; al[0] = r.l;
  r = split1(x0.y); ah[1] = r.h; al[1] = r.l;
  r = split1(x0.z); ah[2] = r.h; al[2] = r.l;
  r = split1(x0.w); ah[3] = r.h; al[3] = r.l;
  r = split1(x1.x); ah[4] = r.h; al[4] = r.l;
  r = split1(x1.y); ah[5] = r.h; al[5] = r.l;
  r = split1(x1.z); ah[6] = r.h; al[6] = r.l;
  r = split1(x1.w); ah[7] = r.h; al[7] = r.l;
}

// async global->LDS DMA, 16 B per lane: dest = (wave-uniform base) + lane*16.
#if __has_builtin(__builtin_amdgcn_global_load_lds)
__device__ __forceinline__ void gl2lds16(const float* g, float* l) {
  __builtin_amdgcn_global_load_lds(
      (const __attribute__((address_space(1))) void*)g,
      (__attribute__((address_space(3))) void*)l, 16, 0, 0);
}
#else
__device__ __forceinline__ void gl2lds16(const float* g, float* l) {
  const int lane = threadIdx.x & 63;
  *(float4*)((char*)l + lane * 16) = *(const float4*)g;
}
#endif

// 4-way combined reciprocal: sum over a d-quad of avn_d / (1 + e_d*ek_d).
__device__ __forceinline__ float grp4(v4f e, v4f ek, v4f av4) {
  const v4f one = {1.f, 1.f, 1.f, 1.f};
  const v4f den = e * ek + one;
  const float AB = den.x * den.y;
  const float CD = den.z * den.w;
  const float n1 = __builtin_fmaf(av4.y, den.x, av4.x * den.y);
  const float n2 = __builtin_fmaf(av4.w, den.z, av4.z * den.w);
  const float N = __builtin_fmaf(n2, AB, n1 * CD);
  return N * RCPF(AB * CD);
}

// ============ Fused single-launch kernel: qkv phase -> grid.sync -> attn ====
// grid 512 x 256 thr, cooperative. Blocks 0..383: qkv (z = r>>7, h, row-tile).
// All 512 blocks: R13 attn phase (q-tile = r&31, bh = r>>5).
// LDS: one 50.4 KB arena, phase-aliased (qkv 50.4 KB / attn 42 KB).
__global__ __launch_bounds__(256) void fused_all(
    const float* __restrict__ Xq, const float* __restrict__ Xk, const float* __restrict__ Xv,
    const float* __restrict__ Wq, const float* __restrict__ Wk, const float* __restrict__ Wv,
    const float* __restrict__ Wo,
    const float* __restrict__ bq, const float* __restrict__ bk, const float* __restrict__ bv,
    const float* __restrict__ bo,
    const float* __restrict__ Aq, const float* __restrict__ Ak, const float* __restrict__ av,
    float* __restrict__ EQ, float* __restrict__ EKt, float* __restrict__ Vw,
    short* __restrict__ WoPk, float* __restrict__ attnW, float* __restrict__ outp)
{
  __shared__ __align__(16) char smem[50432];

  const int tid = threadIdx.x, l = tid & 63, w = tid >> 6;
  const int lm = l & 15, lq = l >> 4;
  const int r = blockIdx.x;

  // ---------------- phase 1: QKV projection + additive-proj + exp2 + packs
  if (r < 384) {
    short (*fragH)[4][64][8] = (short (*)[4][64][8])(smem);          //  8 KB
    short (*fragL)[4][64][8] = (short (*)[4][64][8])(smem + 8192);   //  8 KB
    float (*qs)[68]   = (float (*)[68])(smem + 16384);               // 17 KB
    float (*qs2)[260] = (float (*)[260])(smem + 33792);              // 16.6 KB

    const int z = r >> 7;
    const int rem = r & 127;
    const int h = rem >> 4;
    const int r0 = (rem & 15) * 64;
    const float* X    = (z == 0) ? Xq : (z == 1) ? Xk : Xv;
    const float* W    = (z == 0) ? Wq : (z == 1) ? Wk : Wv;
    const float* bias = (z == 0) ? bq : (z == 1) ? bk : bv;

    v4f acc[4] = {{0.f,0.f,0.f,0.f},{0.f,0.f,0.f,0.f},{0.f,0.f,0.f,0.f},{0.f,0.f,0.f,0.f}};
    const float* xrow = X + (size_t)(r0 + w * 16 + lm) * Dd + lq * 8;

    for (int kt = 0; kt < 16; ++kt) {
      const int buf = kt & 1;
      const float4 xa0 = *(const float4*)&xrow[kt * 32];
      const float4 xa1 = *(const float4*)&xrow[kt * 32 + 4];
      {
        v8s hh, ll;
#pragma unroll
        for (int j = 0; j < 8; j++) {
          const float x = W[(size_t)(kt * 32 + lq * 8 + j) * Dd + h * 64 + w * 16 + lm];
          const HL rr = split1(x);
          hh[j] = rr.h; ll[j] = rr.l;
        }
        *(v8s*)&fragH[buf][w][l][0] = hh;
        *(v8s*)&fragL[buf][w][l][0] = ll;
      }
      __syncthreads();
      v8s ah, al;
      split8v(xa0, xa1, ah, al);
#pragma unroll
      for (int t = 0; t < 4; t++) {
        const v8s bh = *(const v8s*)&fragH[buf][t][l][0];
        const v8s bl = *(const v8s*)&fragL[buf][t][l][0];
        acc[t] = __builtin_amdgcn_mfma_f32_16x16x32_bf16(ah, bh, acc[t], 0, 0, 0);
        acc[t] = __builtin_amdgcn_mfma_f32_16x16x32_bf16(ah, bl, acc[t], 0, 0, 0);
        acc[t] = __builtin_amdgcn_mfma_f32_16x16x32_bf16(al, bh, acc[t], 0, 0, 0);
      }
    }

    if (z == 2) {   // V store + Wo pack + out bias-init
#pragma unroll
      for (int t = 0; t < 4; t++) {
        const int n = h * 64 + t * 16 + lm;
        const float bvv = bias[n];
#pragma unroll
        for (int rr = 0; rr < 4; rr++)
          Vw[(size_t)(r0 + w * 16 + lq * 4 + rr) * Dd + n] = acc[t][rr] + bvv;
      }
      {
        const int tau = rem * 4 + w;              // 0..511
        const int nt = tau >> 4, kt = tau & 15;
        v8s hh, ll;
#pragma unroll
        for (int j = 0; j < 8; j++) {
          const float x = Wo[(size_t)(kt * 32 + lq * 8 + j) * Dd + nt * 16 + lm];
          const HL rr = split1(x);
          hh[j] = rr.h; ll[j] = rr.l;
        }
        *(v8s*)&WoPk[((size_t)tau * 64 + l) * 16 + 0] = hh;
        *(v8s*)&WoPk[((size_t)tau * 64 + l) * 16 + 8] = ll;
      }
      for (int i = tid; i < 4096; i += 256) {
        const int rr2 = i >> 6, cc = i & 63;
        outp[(size_t)(r0 + rr2) * Dd + h * 64 + cc] = bo[h * 64 + cc];
      }
    } else {
#pragma unroll
      for (int t = 0; t < 4; t++) {
        const int n = h * 64 + t * 16 + lm;
        const float bvv = bias[n];
#pragma unroll
        for (int rr = 0; rr < 4; rr++)
          qs[w * 16 + lq * 4 + rr][t * 16 + lm] = acc[t][rr] + bvv;
      }
      __syncthreads();

      const float* Am = (z == 0) ? Aq : Ak;
      v4f a2[4] = {{0.f,0.f,0.f,0.f},{0.f,0.f,0.f,0.f},{0.f,0.f,0.f,0.f},{0.f,0.f,0.f,0.f}};
#pragma unroll
      for (int kt2 = 0; kt2 < 2; ++kt2) {
        v8s ah, al;
        split8p(&qs[w * 16 + lm][kt2 * 32 + lq * 8], ah, al);
#pragma unroll
        for (int t2 = 0; t2 < 4; t2++) {
          v8s bh, bl;
#pragma unroll
          for (int j = 0; j < 8; j++) {
            const float x = Am[(kt2 * 32 + lq * 8 + j) * HDd + t2 * 16 + lm]
                            * 2.885390081777927f;   // 2*log2(e) fold
            const HL rr = split1(x);
            bh[j] = rr.h; bl[j] = rr.l;
          }
          a2[t2] = __builtin_amdgcn_mfma_f32_16x16x32_bf16(ah, bh, a2[t2], 0, 0, 0);
          a2[t2] = __builtin_amdgcn_mfma_f32_16x16x32_bf16(ah, bl, a2[t2], 0, 0, 0);
          a2[t2] = __builtin_amdgcn_mfma_f32_16x16x32_bf16(al, bh, a2[t2], 0, 0, 0);
        }
      }

      if (z == 0) {   // EQ = exp2, row-major
#pragma unroll
        for (int t2 = 0; t2 < 4; t2++)
#pragma unroll
          for (int rr = 0; rr < 4; rr++)
            EQ[(size_t)(r0 + w * 16 + lq * 4 + rr) * Dd + h * 64 + t2 * 16 + lm] = EXP2F(a2[t2][rr]);
      } else {        // EKt: exp2 + transpose to [dt][k*4+dd] via LDS
#pragma unroll
        for (int t2 = 0; t2 < 4; t2++)
#pragma unroll
          for (int rr = 0; rr < 4; rr++)
            qs2[4 * t2 + (lm >> 2)][(w * 16 + lq * 4 + rr) * 4 + (lm & 3)] = EXP2F(a2[t2][rr]);
        __syncthreads();
        const int b = r0 >> 9;
        const size_t base = (size_t)(b * 8 + h) * 16 * 2048 + (size_t)(r0 & 511) * 4;
#pragma unroll
        for (int i = 0; i < 4; i++) {
          const int f = i * 1024 + tid * 4;
          const int dt = f >> 8, c = f & 255;
          *(float4*)&EKt[base + (size_t)dt * 2048 + c] = *(const float4*)&qs2[dt][c];
        }
      }
    }
  }

  // ---------------- grid-wide barrier (device-scope fence included)
  cooperative_groups::this_grid().sync();

  // ---------------- phase 2: attention (R13 structure, verbatim)
  {
    float* uni        = (float*)smem;                        // 33024 B
    float (*eq_s)[64] = (float (*)[64])(smem + 33024);       // 4 KB
    float (*ctx_s)[68]= (float (*)[68])(smem + 37120);       // 4.3 KB
    float* avn        = (float*)(smem + 41472);              // 256 B

    const int q0 = (r & 31) * 16;
    const int bh = r >> 5;
    const int b = bh >> 3, h = bh & 7;

    {
      const float* eqg = EQ + (size_t)(b * Ss + q0 + w * 4 + lq) * Dd
                         + h * HDd + lm * 4;
      gl2lds16(eqg, &eq_s[w * 4][0]);
    }
    if (tid < 64) avn[tid] = -2.f * av[tid];

    const float* ekbase = EKt + (size_t)bh * 16 * 2048;
    gl2lds16(ekbase + w * 512 + l * 4, &uni[w * 512]);
    gl2lds16(ekbase + w * 512 + 256 + l * 4, &uni[w * 512 + 256]);
    __syncthreads();

    const int qg = w * 4;
    float a[4][8];
#pragma unroll
    for (int j = 0; j < 4; j++)
#pragma unroll
      for (int kg = 0; kg < 8; kg++) a[j][kg] = 0.f;

#pragma unroll 1
    for (int dt = 0; dt < 16; ++dt) {
      const int cb = (dt & 1) * 2048;
      const int nb = 2048 - cb;
      const int dtn = (dt < 15) ? dt + 1 : 15;   // clamped (uniform)
      gl2lds16(ekbase + (size_t)dtn * 2048 + w * 512 + l * 4, &uni[nb + w * 512]);
      gl2lds16(ekbase + (size_t)dtn * 2048 + w * 512 + 256 + l * 4, &uni[nb + w * 512 + 256]);

      const v4f av4 = *(const v4f*)&avn[dt * 4];
      const v4f e0 = *(const v4f*)&eq_s[qg + 0][dt * 4];
      const v4f e1 = *(const v4f*)&eq_s[qg + 1][dt * 4];
      const v4f e2 = *(const v4f*)&eq_s[qg + 2][dt * 4];
      const v4f e3 = *(const v4f*)&eq_s[qg + 3][dt * 4];
#pragma unroll
      for (int kg = 0; kg < 8; kg++) {
        const v4f ek = *(const v4f*)&uni[cb + kg * 256 + l * 4];
        a[0][kg] += grp4(e0, ek, av4);
        a[1][kg] += grp4(e1, ek, av4);
        a[2][kg] += grp4(e2, ek, av4);
        a[3][kg] += grp4(e3, ek, av4);
      }
      __syncthreads();
    }

    // in-register softmax per q row; write attnW + sc (sc aliases dead bufs)
#pragma unroll
    for (int j = 0; j < 4; j++) {
      float m = -1e30f;
#pragma unroll
      for (int kg = 0; kg < 8; kg++) m = fmaxf(m, a[j][kg]);
#pragma unroll
      for (int off = 32; off >= 1; off >>= 1) m = fmaxf(m, __shfl_xor(m, off, 64));
      float s = 0.f;
#pragma unroll
      for (int kg = 0; kg < 8; kg++) {
        a[j][kg] = EXP2F((a[j][kg] - m) * 1.4426950408889634f);
        s += a[j][kg];
      }
#pragma unroll
      for (int off = 32; off >= 1; off >>= 1) s += __shfl_xor(s, off, 64);
      const float inv = RCPF(s);
      float* arow = attnW + ((size_t)bh * Ss + q0 + qg + j) * Ss;
#pragma unroll
      for (int kg = 0; kg < 8; kg++) {
        const float wv = a[j][kg] * inv;
        uni[(qg + j) * 516 + kg * 64 + l] = wv;
        arow[kg * 64 + l] = wv;
      }
    }
    __syncthreads();

    // ctx = sc(16x512) @ V(512x64), k-split across waves
    {
      const int rg = (tid >> 4) & 3;
      const int dq = tid & 15;
      const int k0 = w * 128;
      const float* scr0 = &uni[(4 * rg + 0) * 516];
      const float* scr1 = &uni[(4 * rg + 1) * 516];
      const float* scr2 = &uni[(4 * rg + 2) * 516];
      const float* scr3 = &uni[(4 * rg + 3) * 516];
      const float* vb = Vw + (size_t)b * Ss * Dd + h * HDd + dq * 4;
      v4f o0 = {0.f,0.f,0.f,0.f}, o1 = {0.f,0.f,0.f,0.f};
      v4f o2 = {0.f,0.f,0.f,0.f}, o3 = {0.f,0.f,0.f,0.f};
      for (int kk = k0; kk < k0 + 128; kk += 2) {
        const float2 w0 = *(const float2*)&scr0[kk];
        const float2 w1 = *(const float2*)&scr1[kk];
        const float2 w2 = *(const float2*)&scr2[kk];
        const float2 w3 = *(const float2*)&scr3[kk];
        const v4f va = *(const v4f*)&vb[(size_t)kk * Dd];
        const v4f vz = *(const v4f*)&vb[(size_t)(kk + 1) * Dd];
        o0 += w0.x * va + w0.y * vz;
        o1 += w1.x * va + w1.y * vz;
        o2 += w2.x * va + w2.y * vz;
        o3 += w3.x * va + w3.y * vz;
      }
      __syncthreads();               // all sc reads done before partials overwrite
      *(v4f*)&uni[w * 1024 + (4 * rg + 0) * 64 + dq * 4] = o0;
      *(v4f*)&uni[w * 1024 + (4 * rg + 1) * 64 + dq * 4] = o1;
      *(v4f*)&uni[w * 1024 + (4 * rg + 2) * 64 + dq * 4] = o2;
      *(v4f*)&uni[w * 1024 + (4 * rg + 3) * 64 + dq * 4] = o3;
    }
    __syncthreads();
    {  // reduce 4 wave-partials -> ctx_s (padded)
      const int e = tid * 4;
      const int rr = e >> 6, c = e & 63;
      v4f s0 = *(const v4f*)&uni[e];
      s0 += *(const v4f*)&uni[1024 + e];
      s0 += *(const v4f*)&uni[2048 + e];
      s0 += *(const v4f*)&uni[3072 + e];
      *(v4f*)&ctx_s[rr][c] = s0;
    }
    __syncthreads();

    // partial out(16x512) = ctx_s @ Wo[h*64..+63, :], atomic accumulate,
    // head-staggered n-tile order
    {
      v4f oacc[8];
#pragma unroll
      for (int i = 0; i < 8; i++) oacc[i] = (v4f){0.f, 0.f, 0.f, 0.f};
#pragma unroll
      for (int kt2 = 0; kt2 < 2; ++kt2) {
        v8s ah, al;
        split8p(&ctx_s[lm][kt2 * 32 + lq * 8], ah, al);
#pragma unroll
        for (int n8 = 0; n8 < 8; n8++) {
          const int n8i = (n8 + h) & 7;
          const int tau = (w * 8 + n8i) * 16 + 2 * h + kt2;
          const size_t bi = ((size_t)tau * 64 + l) * 16;
          const v8s bh = *(const v8s*)&WoPk[bi + 0];
          const v8s bl = *(const v8s*)&WoPk[bi + 8];
          oacc[n8] = __builtin_amdgcn_mfma_f32_16x16x32_bf16(ah, bh, oacc[n8], 0, 0, 0);
          oacc[n8] = __builtin_amdgcn_mfma_f32_16x16x32_bf16(ah, bl, oacc[n8], 0, 0, 0);
          oacc[n8] = __builtin_amdgcn_mfma_f32_16x16x32_bf16(al, bh, oacc[n8], 0, 0, 0);
        }
      }
#pragma unroll
      for (int n8 = 0; n8 < 8; n8++) {
        const int n8i = (n8 + h) & 7;
        const int n = (w * 8 + n8i) * 16 + lm;
#pragma unroll
        for (int rr = 0; rr < 4; rr++)
          atomicAdd(&outp[(size_t)(b * Ss + q0 + lq * 4 + rr) * Dd + n], oacc[n8][rr]);
      }
    }
  }
}

extern "C" void kernel_launch(void* const* d_in, const int* in_sizes, int n_in,
                              void* d_out, int out_size, void* d_ws, size_t ws_size,
                              hipStream_t stream) {
  (void)in_sizes; (void)n_in; (void)out_size; (void)ws_size;
  const float* query = (const float*)d_in[0];
  const float* key_  = (const float*)d_in[1];
  const float* value = (const float*)d_in[2];
  const float* Wq    = (const float*)d_in[3];
  const float* bq    = (const float*)d_in[4];
  const float* Wk    = (const float*)d_in[5];
  const float* bk    = (const float*)d_in[6];
  const float* Wv    = (const float*)d_in[7];
  const float* bv    = (const float*)d_in[8];
  const float* Wo    = (const float*)d_in[9];
  const float* bo    = (const float*)d_in[10];
  const float* Aq    = (const float*)d_in[11];
  const float* Ak    = (const float*)d_in[12];
  const float* av    = (const float*)d_in[13];

  float* outp = (float*)d_out;                  // 2 MB
  float* attn = outp + (size_t)BS * Dd;         // 16 MB

  // ws: EQ/EKt/V fp32 (6 MB) + Wo pack (1 MB)
  float* ws  = (float*)d_ws;
  float* EQ  = ws;
  float* EKt = ws + (size_t)BS * Dd;
  float* Vw  = ws + 2 * (size_t)BS * Dd;
  short* WoPk = (short*)(ws + 3 * (size_t)BS * Dd);

  void* args[] = {
    (void*)&query, (void*)&key_, (void*)&value,
    (void*)&Wq, (void*)&Wk, (void*)&Wv, (void*)&Wo,
    (void*)&bq, (void*)&bk, (void*)&bv, (void*)&bo,
    (void*)&Aq, (void*)&Ak, (void*)&av,
    (void*)&EQ, (void*)&EKt, (void*)&Vw,
    (void*)&WoPk, (void*)&attn, (void*)&outp
  };
  hipLaunchCooperativeKernel((void*)fused_all, dim3(512), dim3(256),
                             args, 0, stream);
}

// Round 16
// 160.578 us; speedup vs baseline: 1.5189x; 1.5189x over previous
//
#include <hip/hip_runtime.h>
#include <math.h>

#define Bb 2
#define Ss 512
#define Dd 512
#define Hh 8
#define HDd 64
#define BS (Bb*Ss)

#if __has_builtin(__builtin_amdgcn_exp2f)
#define EXP2F(x) __builtin_amdgcn_exp2f(x)
#else
#define EXP2F(x) exp2f(x)
#endif
#if __has_builtin(__builtin_amdgcn_rcpf)
#define RCPF(x) __builtin_amdgcn_rcpf(x)
#else
#define RCPF(x) (1.0f/(x))
#endif

typedef float v4f __attribute__((ext_vector_type(4)));
typedef short v8s __attribute__((ext_vector_type(8)));

struct HL { short h, l; };

// RNE fp32 -> bf16 split: x ~= hi + lo, both bf16-representable.
__device__ __forceinline__ HL split1(float x) {
  unsigned u = __builtin_bit_cast(unsigned, x);
  unsigned h = (u + 0x7fffu + ((u >> 16) & 1u)) >> 16;
  float hf = __builtin_bit_cast(float, h << 16);
  float lo = x - hf;
  unsigned ul = __builtin_bit_cast(unsigned, lo);
  unsigned l = (ul + 0x7fffu + ((ul >> 16) & 1u)) >> 16;
  HL r; r.h = (short)h; r.l = (short)l;
  return r;
}

__device__ __forceinline__ void split8p(const float* __restrict__ xp, v8s& ah, v8s& al) {
#pragma unroll
  for (int j = 0; j < 8; j++) {
    const HL r = split1(xp[j]);
    ah[j] = r.h; al[j] = r.l;
  }
}

__device__ __forceinline__ void split8v(float4 x0, float4 x1, v8s& ah, v8s& al) {
  HL r;
  r = split1(x0.x); ah[0] = r.h; al[0] = r.l;
  r = split1(x0.y); ah[1] = r.h; al[1] = r.l;
  r = split1(x0.z); ah[2] = r.h; al[2] = r.l;
  r = split1(x0.w); ah[3] = r.h; al[3] = r.l;
  r = split1(x1.x); ah[4] = r.h; al[4] = r.l;
  r = split1(x1.y); ah[5] = r.h; al[5] = r.l;
  r = split1(x1.z); ah[6] = r.h; al[6] = r.l;
  r = split1(x1.w); ah[7] = r.h; al[7] = r.l;
}

// async global->LDS DMA, 16 B per lane: dest = (wave-uniform base) + lane*16.
#if __has_builtin(__builtin_amdgcn_global_load_lds)
__device__ __forceinline__ void gl2lds16(const float* g, float* l) {
  __builtin_amdgcn_global_load_lds(
      (const __attribute__((address_space(1))) void*)g,
      (__attribute__((address_space(3))) void*)l, 16, 0, 0);
}
#else
__device__ __forceinline__ void gl2lds16(const float* g, float* l) {
  const int lane = threadIdx.x & 63;
  *(float4*)((char*)l + lane * 16) = *(const float4*)g;
}
#endif

// ============ K1: fused QKV projection + additive-proj + exp2 + Wo pack ====
// (R13 verbatim; z=2 also bias-inits out)
__global__ __launch_bounds__(256) void qkv_all(
    const float* __restrict__ Xq, const float* __restrict__ Xk, const float* __restrict__ Xv,
    const float* __restrict__ Wq, const float* __restrict__ Wk, const float* __restrict__ Wv,
    const float* __restrict__ Wo,
    const float* __restrict__ bq, const float* __restrict__ bk, const float* __restrict__ bv,
    const float* __restrict__ bo,
    const float* __restrict__ Aq, const float* __restrict__ Ak,
    float* __restrict__ EQ, float* __restrict__ EKt, float* __restrict__ Vw,
    short* __restrict__ WoPk, float* __restrict__ outp)
{
  __shared__ __align__(16) short fragH[2][4][64][8];
  __shared__ __align__(16) short fragL[2][4][64][8];
  __shared__ float qs[64][68];
  __shared__ float qs2[16][260];

  const int z = blockIdx.z;
  const float* X    = (z == 0) ? Xq : (z == 1) ? Xk : Xv;
  const float* W    = (z == 0) ? Wq : (z == 1) ? Wk : Wv;
  const float* bias = (z == 0) ? bq : (z == 1) ? bk : bv;
  const int tid = threadIdx.x, l = tid & 63, w = tid >> 6;
  const int lm = l & 15, lq = l >> 4;
  const int h = blockIdx.x;
  const int r0 = blockIdx.y * 64;

  v4f acc[4] = {{0.f,0.f,0.f,0.f},{0.f,0.f,0.f,0.f},{0.f,0.f,0.f,0.f},{0.f,0.f,0.f,0.f}};
  const float* xrow = X + (size_t)(r0 + w * 16 + lm) * Dd + lq * 8;

  for (int kt = 0; kt < 16; ++kt) {
    const int buf = kt & 1;
    const float4 xa0 = *(const float4*)&xrow[kt * 32];
    const float4 xa1 = *(const float4*)&xrow[kt * 32 + 4];
    {
      v8s hh, ll;
#pragma unroll
      for (int j = 0; j < 8; j++) {
        const float x = W[(size_t)(kt * 32 + lq * 8 + j) * Dd + h * 64 + w * 16 + lm];
        const HL r = split1(x);
        hh[j] = r.h; ll[j] = r.l;
      }
      *(v8s*)&fragH[buf][w][l][0] = hh;
      *(v8s*)&fragL[buf][w][l][0] = ll;
    }
    __syncthreads();
    v8s ah, al;
    split8v(xa0, xa1, ah, al);
#pragma unroll
    for (int t = 0; t < 4; t++) {
      const v8s bh = *(const v8s*)&fragH[buf][t][l][0];
      const v8s bl = *(const v8s*)&fragL[buf][t][l][0];
      acc[t] = __builtin_amdgcn_mfma_f32_16x16x32_bf16(ah, bh, acc[t], 0, 0, 0);
      acc[t] = __builtin_amdgcn_mfma_f32_16x16x32_bf16(ah, bl, acc[t], 0, 0, 0);
      acc[t] = __builtin_amdgcn_mfma_f32_16x16x32_bf16(al, bh, acc[t], 0, 0, 0);
    }
  }

  if (z == 2) {   // V store + Wo pack + out bias-init
#pragma unroll
    for (int t = 0; t < 4; t++) {
      const int n = h * 64 + t * 16 + lm;
      const float bvv = bias[n];
#pragma unroll
      for (int r = 0; r < 4; r++)
        Vw[(size_t)(r0 + w * 16 + lq * 4 + r) * Dd + n] = acc[t][r] + bvv;
    }
    {
      const int tau = (blockIdx.y * 8 + h) * 4 + w;
      const int nt = tau >> 4, kt = tau & 15;
      v8s hh, ll;
#pragma unroll
      for (int j = 0; j < 8; j++) {
        const float x = Wo[(size_t)(kt * 32 + lq * 8 + j) * Dd + nt * 16 + lm];
        const HL r = split1(x);
        hh[j] = r.h; ll[j] = r.l;
      }
      *(v8s*)&WoPk[((size_t)tau * 64 + l) * 16 + 0] = hh;
      *(v8s*)&WoPk[((size_t)tau * 64 + l) * 16 + 8] = ll;
    }
    for (int i = tid; i < 4096; i += 256) {
      const int rr2 = i >> 6, cc = i & 63;
      outp[(size_t)(r0 + rr2) * Dd + h * 64 + cc] = bo[h * 64 + cc];
    }
    return;
  }

#pragma unroll
  for (int t = 0; t < 4; t++) {
    const int n = h * 64 + t * 16 + lm;
    const float bvv = bias[n];
#pragma unroll
    for (int r = 0; r < 4; r++)
      qs[w * 16 + lq * 4 + r][t * 16 + lm] = acc[t][r] + bvv;
  }
  __syncthreads();

  const float* Am = (z == 0) ? Aq : Ak;
  v4f a2[4] = {{0.f,0.f,0.f,0.f},{0.f,0.f,0.f,0.f},{0.f,0.f,0.f,0.f},{0.f,0.f,0.f,0.f}};
#pragma unroll
  for (int kt2 = 0; kt2 < 2; ++kt2) {
    v8s ah, al;
    split8p(&qs[w * 16 + lm][kt2 * 32 + lq * 8], ah, al);
#pragma unroll
    for (int t2 = 0; t2 < 4; t2++) {
      v8s bh, bl;
#pragma unroll
      for (int j = 0; j < 8; j++) {
        const float x = Am[(kt2 * 32 + lq * 8 + j) * HDd + t2 * 16 + lm]
                        * 2.885390081777927f;
        const HL r = split1(x);
        bh[j] = r.h; bl[j] = r.l;
      }
      a2[t2] = __builtin_amdgcn_mfma_f32_16x16x32_bf16(ah, bh, a2[t2], 0, 0, 0);
      a2[t2] = __builtin_amdgcn_mfma_f32_16x16x32_bf16(ah, bl, a2[t2], 0, 0, 0);
      a2[t2] = __builtin_amdgcn_mfma_f32_16x16x32_bf16(al, bh, a2[t2], 0, 0, 0);
    }
  }

  if (z == 0) {
#pragma unroll
    for (int t2 = 0; t2 < 4; t2++)
#pragma unroll
      for (int rr = 0; rr < 4; rr++)
        EQ[(size_t)(r0 + w * 16 + lq * 4 + rr) * Dd + h * 64 + t2 * 16 + lm] = EXP2F(a2[t2][rr]);
  } else {
#pragma unroll
    for (int t2 = 0; t2 < 4; t2++)
#pragma unroll
      for (int rr = 0; rr < 4; rr++)
        qs2[4 * t2 + (lm >> 2)][(w * 16 + lq * 4 + rr) * 4 + (lm & 3)] = EXP2F(a2[t2][rr]);
    __syncthreads();
    const int b = r0 >> 9;
    const size_t base = (size_t)(b * 8 + h) * 16 * 2048 + (size_t)(r0 & 511) * 4;
#pragma unroll
    for (int i = 0; i < 4; i++) {
      const int f = i * 1024 + tid * 4;
      const int dt = f >> 8, c = f & 255;
      *(float4*)&EKt[base + (size_t)dt * 2048 + c] = *(const float4*)&qs2[dt][c];
    }
  }
}

// 4-way combined reciprocal: sum over a d-quad of avn_d / (1 + e_d*ek_d).
__device__ __forceinline__ float grp4(v4f e, v4f ek, v4f av4) {
  const v4f one = {1.f, 1.f, 1.f, 1.f};
  const v4f den = e * ek + one;
  const float AB = den.x * den.y;
  const float CD = den.z * den.w;
  const float n1 = __builtin_fmaf(av4.y, den.x, av4.x * den.y);
  const float n2 = __builtin_fmaf(av4.w, den.z, av4.z * den.w);
  const float N = __builtin_fmaf(n2, AB, n1 * CD);
  return N * RCPF(AB * CD);
}

// ============ K2: attention + fused out-GEMM ===============================
// R13 structure with a 4-buffer (4x8KB) DMA rotation: 2 slices computed per
// barrier interval -> 8 score-loop barriers instead of 16. Grid-capped at
// 2 blocks/CU, so the VGPR increase from 2-slice ds_read hoisting is free.
__global__ __launch_bounds__(256) void attn_kernel(
    const float* __restrict__ EQ, const float* __restrict__ EKt,
    const float* __restrict__ V, const float* __restrict__ av,
    const short* __restrict__ WoPk,
    float* __restrict__ attnW, float* __restrict__ outp)
{
  __shared__ __align__(16) float uni[8256];     // 4x2048 dma bufs (32KB) | sc[16][516] | ctx partials
  __shared__ __align__(16) float eq_s[16][64];  // 4 KB
  __shared__ __align__(16) float ctx_s[16][68]; // padded
  __shared__ float avn[64];

  const int tid = threadIdx.x, l = tid & 63, w = tid >> 6;
  const int lm = l & 15, lq = l >> 4;
  const int q0 = blockIdx.x * 16;
  const int bh = blockIdx.y;
  const int b = bh >> 3, h = bh & 7;

  // eq tile via DMA: wave w -> rows 4w..4w+3; lane l -> row 4w+lq, col lm*4
  {
    const float* eqg = EQ + (size_t)(b * Ss + q0 + w * 4 + lq) * Dd
                       + h * HDd + lm * 4;
    gl2lds16(eqg, &eq_s[w * 4][0]);
  }
  if (tid < 64) avn[tid] = -2.f * av[tid];

  const float* ekbase = EKt + (size_t)bh * 16 * 2048;
  // preload slices 0,1 into bufs 0,1
#pragma unroll
  for (int s = 0; s < 2; ++s) {
    gl2lds16(ekbase + (size_t)s * 2048 + w * 512 + l * 4,
             &uni[s * 2048 + w * 512]);
    gl2lds16(ekbase + (size_t)s * 2048 + w * 512 + 256 + l * 4,
             &uni[s * 2048 + w * 512 + 256]);
  }
  __syncthreads();

  const int qg = w * 4;
  float a[4][8];
#pragma unroll
  for (int j = 0; j < 4; j++)
#pragma unroll
    for (int kg = 0; kg < 8; kg++) a[j][kg] = 0.f;

#pragma unroll 1
  for (int it = 0; it < 8; ++it) {
    // DMA slices 2it+2, 2it+3 into the buffers freed at the last barrier
    if (it < 7) {
      const int p0 = 2 * it + 2, p1 = 2 * it + 3;
      gl2lds16(ekbase + (size_t)p0 * 2048 + w * 512 + l * 4,
               &uni[(p0 & 3) * 2048 + w * 512]);
      gl2lds16(ekbase + (size_t)p0 * 2048 + w * 512 + 256 + l * 4,
               &uni[(p0 & 3) * 2048 + w * 512 + 256]);
      gl2lds16(ekbase + (size_t)p1 * 2048 + w * 512 + l * 4,
               &uni[(p1 & 3) * 2048 + w * 512]);
      gl2lds16(ekbase + (size_t)p1 * 2048 + w * 512 + 256 + l * 4,
               &uni[(p1 & 3) * 2048 + w * 512 + 256]);
    }
    // compute slices 2it, 2it+1
#pragma unroll
    for (int ss = 0; ss < 2; ++ss) {
      const int dt = 2 * it + ss;
      const int cb = (dt & 3) * 2048;
      const v4f av4 = *(const v4f*)&avn[dt * 4];
      const v4f e0 = *(const v4f*)&eq_s[qg + 0][dt * 4];
      const v4f e1 = *(const v4f*)&eq_s[qg + 1][dt * 4];
      const v4f e2 = *(const v4f*)&eq_s[qg + 2][dt * 4];
      const v4f e3 = *(const v4f*)&eq_s[qg + 3][dt * 4];
#pragma unroll
      for (int kg = 0; kg < 8; kg++) {
        const v4f ek = *(const v4f*)&uni[cb + kg * 256 + l * 4];
        a[0][kg] += grp4(e0, ek, av4);
        a[1][kg] += grp4(e1, ek, av4);
        a[2][kg] += grp4(e2, ek, av4);
        a[3][kg] += grp4(e3, ek, av4);
      }
    }
    __syncthreads();   // slices 2it,2it+1 consumed; DMA for 2it+2,2it+3 drained
  }

  // in-register softmax per q row; write attnW + sc (sc aliases dead buffers)
#pragma unroll
  for (int j = 0; j < 4; j++) {
    float m = -1e30f;
#pragma unroll
    for (int kg = 0; kg < 8; kg++) m = fmaxf(m, a[j][kg]);
#pragma unroll
    for (int off = 32; off >= 1; off >>= 1) m = fmaxf(m, __shfl_xor(m, off, 64));
    float s = 0.f;
#pragma unroll
    for (int kg = 0; kg < 8; kg++) {
      a[j][kg] = EXP2F((a[j][kg] - m) * 1.4426950408889634f);
      s += a[j][kg];
    }
#pragma unroll
    for (int off = 32; off >= 1; off >>= 1) s += __shfl_xor(s, off, 64);
    const float inv = RCPF(s);
    float* arow = attnW + ((size_t)bh * Ss + q0 + qg + j) * Ss;
#pragma unroll
    for (int kg = 0; kg < 8; kg++) {
      const float wv = a[j][kg] * inv;
      uni[(qg + j) * 516 + kg * 64 + l] = wv;
      arow[kg * 64 + l] = wv;
    }
  }
  __syncthreads();

  // ---- ctx = sc(16x512) @ V(512x64), k-split across waves (R13 verbatim)
  {
    const int rg = (tid >> 4) & 3;
    const int dq = tid & 15;
    const int k0 = w * 128;
    const float* scr0 = &uni[(4 * rg + 0) * 516];
    const float* scr1 = &uni[(4 * rg + 1) * 516];
    const float* scr2 = &uni[(4 * rg + 2) * 516];
    const float* scr3 = &uni[(4 * rg + 3) * 516];
    const float* vb = V + (size_t)b * Ss * Dd + h * HDd + dq * 4;
    v4f o0 = {0.f,0.f,0.f,0.f}, o1 = {0.f,0.f,0.f,0.f};
    v4f o2 = {0.f,0.f,0.f,0.f}, o3 = {0.f,0.f,0.f,0.f};
    for (int kk = k0; kk < k0 + 128; kk += 2) {
      const float2 w0 = *(const float2*)&scr0[kk];
      const float2 w1 = *(const float2*)&scr1[kk];
      const float2 w2 = *(const float2*)&scr2[kk];
      const float2 w3 = *(const float2*)&scr3[kk];
      const v4f va = *(const v4f*)&vb[(size_t)kk * Dd];
      const v4f vz = *(const v4f*)&vb[(size_t)(kk + 1) * Dd];
      o0 += w0.x * va + w0.y * vz;
      o1 += w1.x * va + w1.y * vz;
      o2 += w2.x * va + w2.y * vz;
      o3 += w3.x * va + w3.y * vz;
    }
    __syncthreads();               // all sc reads done before partials overwrite
    *(v4f*)&uni[w * 1024 + (4 * rg + 0) * 64 + dq * 4] = o0;
    *(v4f*)&uni[w * 1024 + (4 * rg + 1) * 64 + dq * 4] = o1;
    *(v4f*)&uni[w * 1024 + (4 * rg + 2) * 64 + dq * 4] = o2;
    *(v4f*)&uni[w * 1024 + (4 * rg + 3) * 64 + dq * 4] = o3;
  }
  __syncthreads();
  {  // reduce 4 wave-partials -> ctx_s (padded)
    const int e = tid * 4;
    const int r = e >> 6, c = e & 63;
    v4f s0 = *(const v4f*)&uni[e];
    s0 += *(const v4f*)&uni[1024 + e];
    s0 += *(const v4f*)&uni[2048 + e];
    s0 += *(const v4f*)&uni[3072 + e];
    *(v4f*)&ctx_s[r][c] = s0;
  }
  __syncthreads();

  // partial out(16x512) = ctx_s @ Wo[h*64..+63, :], atomic accumulate,
  // head-staggered n-tile order (R13 verbatim).
  {
    v4f oacc[8];
#pragma unroll
    for (int i = 0; i < 8; i++) oacc[i] = (v4f){0.f, 0.f, 0.f, 0.f};
#pragma unroll
    for (int kt2 = 0; kt2 < 2; ++kt2) {
      v8s ah, al;
      split8p(&ctx_s[lm][kt2 * 32 + lq * 8], ah, al);
#pragma unroll
      for (int n8 = 0; n8 < 8; n8++) {
        const int n8i = (n8 + h) & 7;
        const int tau = (w * 8 + n8i) * 16 + 2 * h + kt2;
        const size_t bi = ((size_t)tau * 64 + l) * 16;
        const v8s bh = *(const v8s*)&WoPk[bi + 0];
        const v8s bl = *(const v8s*)&WoPk[bi + 8];
        oacc[n8] = __builtin_amdgcn_mfma_f32_16x16x32_bf16(ah, bh, oacc[n8], 0, 0, 0);
        oacc[n8] = __builtin_amdgcn_mfma_f32_16x16x32_bf16(ah, bl, oacc[n8], 0, 0, 0);
        oacc[n8] = __builtin_amdgcn_mfma_f32_16x16x32_bf16(al, bh, oacc[n8], 0, 0, 0);
      }
    }
#pragma unroll
    for (int n8 = 0; n8 < 8; n8++) {
      const int n8i = (n8 + h) & 7;
      const int n = (w * 8 + n8i) * 16 + lm;
#pragma unroll
      for (int r = 0; r < 4; r++)
        atomicAdd(&outp[(size_t)(b * Ss + q0 + lq * 4 + r) * Dd + n], oacc[n8][r]);
    }
  }
}

extern "C" void kernel_launch(void* const* d_in, const int* in_sizes, int n_in,
                              void* d_out, int out_size, void* d_ws, size_t ws_size,
                              hipStream_t stream) {
  (void)in_sizes; (void)n_in; (void)out_size; (void)ws_size;
  const float* query = (const float*)d_in[0];
  const float* key_  = (const float*)d_in[1];
  const float* value = (const float*)d_in[2];
  const float* Wq    = (const float*)d_in[3];
  const float* bq    = (const float*)d_in[4];
  const float* Wk    = (const float*)d_in[5];
  const float* bk    = (const float*)d_in[6];
  const float* Wv    = (const float*)d_in[7];
  const float* bv    = (const float*)d_in[8];
  const float* Wo    = (const float*)d_in[9];
  const float* bo    = (const float*)d_in[10];
  const float* Aq    = (const float*)d_in[11];
  const float* Ak    = (const float*)d_in[12];
  const float* av    = (const float*)d_in[13];

  float* outp = (float*)d_out;                  // 2 MB
  float* attn = outp + (size_t)BS * Dd;         // 16 MB

  // ws: EQ/EKt/V fp32 (6 MB) + Wo pack (1 MB)
  float* ws  = (float*)d_ws;
  float* EQ  = ws;
  float* EKt = ws + (size_t)BS * Dd;
  float* Vw  = ws + 2 * (size_t)BS * Dd;
  short* WoPk = (short*)(ws + 3 * (size_t)BS * Dd);

  qkv_all<<<dim3(8, 16, 3), 256, 0, stream>>>(query, key_, value,
      Wq, Wk, Wv, Wo, bq, bk, bv, bo, Aq, Ak, EQ, EKt, Vw, WoPk, outp);
  attn_kernel<<<dim3(32, 16), 256, 0, stream>>>(EQ, EKt, Vw, av,
      WoPk, attn, outp);
}